// Round 3
// baseline (3845.714 us; speedup 1.0000x reference)
//
#include <hip/hip_runtime.h>
#include <hip/hip_bf16.h>
#include <math.h>

// ---------------------------------------------------------------------------
// PointNet++ Set Abstraction: FPS -> kNN -> grouped MLP(6->32->32->64) with
// BatchNorm(training stats) + ReLU -> max over K.
// B=8, N=8192, S=2048, K=32. All fp32.
//
// d_out layout (floats): new_xyz [8,3,2048] | new_points [8,64,2048] | fps_idx [8,2048]
// ---------------------------------------------------------------------------

#define NB 8
#define NN 8192
#define NS 2048
#define NK 32

// ---------------- prep: transpose to [B,N,4] with w = |p|^2 -----------------
__global__ __launch_bounds__(256) void prep_kernel(const float* __restrict__ xyz,
                                                   const float* __restrict__ pts,
                                                   float4* __restrict__ xyz4,
                                                   float4* __restrict__ pts4) {
  int g = blockIdx.x * 256 + threadIdx.x;      // 65536 = B*N
  int b = g >> 13, n = g & 8191;
  const float* xb = xyz + b * 3 * NN;
  float x = xb[n], y = xb[NN + n], z = xb[2 * NN + n];
  xyz4[g] = make_float4(x, y, z, fmaf(x, x, fmaf(y, y, z * z)));
  const float* pb = pts + b * 3 * NN;
  pts4[g] = make_float4(pb[n], pb[NN + n], pb[2 * NN + n], 0.f);
}

// ---------------- FPS v4 ----------------------------------------------------
// History: R1 (512thr x 16pt) = 1785us, issue-bound: distance work is FIXED
// (8192pts x 9 VALU / 64 / 4SIMD x 2cyc = 576 cyc/iter/CU) but the reduce
// TAIL was paid by 2 waves/SIMD (barrier-synced => redundant, no hiding).
// R2 (inline-asm v_pk_*) REGRESSED to 1957us - asm blobs broke scheduling.
// R3 (this): 256thr x 32pt = 1 wave/SIMD:
//   * tail issue paid once per SIMD, not twice.
//   * guarded index scan (only waves holding a wave-max candidate pay),
//     restructured as bitmask + OR-tree + ffs: depth ~7 vs 32-deep cndmask.
//   * per-thread max as explicit pairwise tree (depth 5): no co-resident wave
//     to hide a 31-deep fmax chain at 1 wave/SIMD.
//   * distance core: plain scalar RN ops under contract(off) (known-exact,
//     known-good R1 codegen). No asm (R2 lesson), no asm reg pin (R0 lesson).
// Exactness invariant: same RN ops, same order, same tie-breaks as reference
// -> fps_idx bit-exact (absmax must stay exactly 2.976562).
template <int CTRL>
__device__ __forceinline__ float dpp_max(float v) {
  int o = __builtin_amdgcn_update_dpp(__float_as_int(v), __float_as_int(v),
                                      CTRL, 0xf, 0xf, false);
  return fmaxf(v, __int_as_float(o));
}

__global__ __launch_bounds__(256, 1) void fps_kernel(const float4* __restrict__ xyz4,
                                                     float* __restrict__ out_nxyz,
                                                     float* __restrict__ out_fps,
                                                     float4* __restrict__ nxyz4) {
#pragma clang fp contract(off)
  int b = blockIdx.x, tid = threadIdx.x;
  int lane = tid & 63, wid = tid >> 6;           // 4 waves, 1 per SIMD
  __shared__ float4 tbl[NN];                     // 128 KB winner-coord table
  __shared__ unsigned long long kslot[2][4];
  const float4* xb = xyz4 + b * NN;

  // thread owns 32 consecutive points [tid*32, tid*32+32): lane order == gid order
  float px[32], py[32], pz[32], dist[32];
#pragma unroll
  for (int j = 0; j < 32; ++j) {
    float4 t = xb[(tid << 5) + j];
    tbl[(tid << 5) + j] = t;
    px[j] = t.x; py[j] = t.y; pz[j] = t.z;
    dist[j] = 1e10f;
  }

  float4 c0 = xb[0];
  float cx = c0.x, cy = c0.y, cz = c0.z;
  float* onx = out_nxyz + b * 3 * NS;
  if (tid == 0) {
    nxyz4[b * NS] = c0;
    onx[0] = c0.x;
    onx[NS] = c0.y;
    onx[2 * NS] = c0.z;
    out_fps[b * NS] = 0.f;
  }
  // NOTE: no barrier needed before first tbl read: the first in-loop
  // __syncthreads (iter s=1) orders every thread's tbl writes before any read.

  for (int s = 1; s < NS; ++s) {
    // exact (no-FMA, RN, left-to-right) distance + running min: 9 VALU/pt.
#pragma unroll
    for (int j = 0; j < 32; ++j) {
      float dx = px[j] - cx;
      float dy = py[j] - cy;
      float dz = pz[j] - cz;
      float d = (dx * dx + dy * dy) + dz * dz;   // contract(off) => pure mul/add
      dist[j] = fminf(dist[j], d);
    }
    // per-thread max value: pairwise tree, depth 5 (~20cy, no 31-deep chain)
    float t16[16];
#pragma unroll
    for (int j = 0; j < 16; ++j) t16[j] = fmaxf(dist[j], dist[j + 16]);
    float t8[8];
#pragma unroll
    for (int j = 0; j < 8; ++j) t8[j] = fmaxf(t16[j], t16[j + 8]);
    float t4[4];
#pragma unroll
    for (int j = 0; j < 4; ++j) t4[j] = fmaxf(t8[j], t8[j + 4]);
    float best = fmaxf(fmaxf(t4[0], t4[2]), fmaxf(t4[1], t4[3]));

    // wave64 max via DPP (all VALU, no LDS): result valid in lane 63
    float mm = best;
    mm = dpp_max<0x111>(mm);  // row_shr:1
    mm = dpp_max<0x112>(mm);  // row_shr:2
    mm = dpp_max<0x114>(mm);  // row_shr:4
    mm = dpp_max<0x118>(mm);  // row_shr:8
    mm = dpp_max<0x142>(mm);  // row_bcast:15
    mm = dpp_max<0x143>(mm);  // row_bcast:31
    float wmax = __int_as_float(__builtin_amdgcn_readlane(__float_as_int(mm), 63));

    unsigned long long bl = __ballot(best == wmax);
    int l0 = __ffsll(bl) - 1;                 // lowest lane = lowest gid

    // guarded local-index scan: only waves holding a candidate pay for it.
    // bitmask + OR-tree + ffs: lowest matching j, dep-depth ~7 not 32.
    int bj = 0;
    if (best == wmax) {
      unsigned bits[32];
#pragma unroll
      for (int j = 0; j < 32; ++j) bits[j] = (dist[j] == best) ? (1u << j) : 0u;
#pragma unroll
      for (int j = 0; j < 16; ++j) bits[j] |= bits[j + 16];
#pragma unroll
      for (int j = 0; j < 8; ++j) bits[j] |= bits[j + 8];
#pragma unroll
      for (int j = 0; j < 4; ++j) bits[j] |= bits[j + 4];
      unsigned mask = (bits[0] | bits[2]) | (bits[1] | bits[3]);
      bj = __ffs(mask) - 1;
    }
    int gw = __builtin_amdgcn_readlane((tid << 5) + bj, l0);

    if (lane == 0)
      kslot[s & 1][wid] = (((unsigned long long)__float_as_uint(wmax)) << 32) |
                          (unsigned)(8191 - gw);  // u64-max => max val, min gid
    __syncthreads();

    // redundant block-wide reduce over 4 wave slots (2x b128 broadcast reads)
    const ulonglong2* kv = (const ulonglong2*)kslot[s & 1];
    ulonglong2 q0 = kv[0], q1 = kv[1];
    unsigned long long a0 = q0.x > q0.y ? q0.x : q0.y;
    unsigned long long a1 = q1.x > q1.y ? q1.x : q1.y;
    unsigned long long km = a0 > a1 ? a0 : a1;
    int gid = 8191 - (int)((unsigned)km & 0x1FFFu);
    gid = __builtin_amdgcn_readfirstlane(gid);   // uniform -> scalar addr math

    float4 c = tbl[gid];  // LDS broadcast read: centroid off the L2 path
    cx = c.x; cy = c.y; cz = c.z;
    if (tid == 0) {
      nxyz4[b * NS + s] = c;
      onx[s] = c.x;
      onx[NS + s] = c.y;
      onx[2 * NS + s] = c.z;
      out_fps[b * NS + s] = (float)gid;
    }
    // single barrier/iter: parity slot kslot[s&1]; iter s+2's write can only
    // happen after barrier s+1, which requires all threads done reading iter s
  }
}

// ---------------- kNN: idx packed into low 13 mantissa bits -----------------
__device__ __forceinline__ void insert32(float (&a)[32], float f) {
  // sorted ascending; keep 32 smallest. new[i] = min(a[i], max(a[i-1], f))
#pragma unroll
  for (int i = 31; i >= 1; --i) a[i] = fminf(a[i], fmaxf(a[i - 1], f));
  a[0] = fminf(a[0], f);
}

__global__ __launch_bounds__(256) void knn_kernel(const float4* __restrict__ xyz4,
                                                  const float4* __restrict__ nxyz4,
                                                  int* __restrict__ knn) {
  __shared__ float lbuf[256][33];  // +1 pad: conflict-free
  int b = blockIdx.x >> 5, tile = blockIdx.x & 31;
  int tid = threadIdx.x;
  int q = tid & 63, chunk = tid >> 6;  // 64 queries x 4 ref-chunks
  float4 Q = nxyz4[b * NS + tile * 64 + q];
  float qq = Q.w;
  float mx = -2.f * Q.x, my = -2.f * Q.y, mz = -2.f * Q.z;
  float arr[32];
#pragma unroll
  for (int i = 0; i < 32; ++i) arr[i] = __uint_as_float(0x7f7fffffu);

  const float4* refs = xyz4 + b * NN + chunk * 2048;
  int rbase = chunk * 2048;
  for (int r = 0; r < 2048; ++r) {
    float4 R = refs[r];  // uniform per wave -> scalar load
    float d = fmaf(R.x, mx, fmaf(R.y, my, fmaf(R.z, mz, R.w + qq)));
    d = fmaxf(d, 0.f);
    float f = __uint_as_float((__float_as_uint(d) & 0xFFFFE000u) | (unsigned)(rbase + r));
    if (f < arr[31]) insert32(arr, f);
  }
#pragma unroll
  for (int i = 0; i < 32; ++i) lbuf[tid][i] = arr[i];
  __syncthreads();
  if (tid < 64) {  // merge 4 chunks for query tid
    for (int c = 1; c < 4; ++c)
      for (int i = 0; i < 32; ++i) {
        float f = lbuf[c * 64 + tid][i];
        if (f < arr[31]) insert32(arr, f);
      }
    int base = (b * NS + tile * 64 + tid) * NK;
#pragma unroll
    for (int i = 0; i < 32; ++i) knn[base + i] = (int)(__float_as_uint(arr[i]) & 0x1FFFu);
  }
}

// ---------------- MLP passes (recompute; BN needs global stats) -------------
// STAGE 0: y0 stats | 1: ->y1 stats | 2: ->y2 stats | 3: full + maxK + out
template <int STAGE>
__global__ __launch_bounds__(256) void mlp_kernel(
    const float4* __restrict__ xyz4, const float4* __restrict__ pts4,
    const float4* __restrict__ nxyz4, const int* __restrict__ knn,
    const float* __restrict__ w0, const float* __restrict__ w1,
    const float* __restrict__ w2, const float* __restrict__ ab,
    float* __restrict__ partials, float* __restrict__ out_np) {
  constexpr int C = (STAGE == 2) ? 64 : 32;              // stats channels
  constexpr int SM = (STAGE == 3) ? 8 * 64 * 32 : 512;   // floats
  __shared__ float smem[SM];
  int blk = blockIdx.x;
  int b = blk >> 6, s0 = (blk & 63) * 32;
  int tid = threadIdx.x, sl = tid & 31, ksec = tid >> 5;
  int lane = tid & 63, wid = tid >> 6;
  int s = s0 + sl;
  float4 Q = nxyz4[b * NS + s];
  const float4* xb = xyz4 + b * NN;
  const float4* pb = pts4 + b * NN;
  const int* kb = knn + (b * NS + s) * NK + ksec * 4;

  float acc1[(STAGE == 3) ? 64 : C];
  float acc2[(STAGE == 3) ? 1 : C];
  if constexpr (STAGE == 3) {
#pragma unroll
    for (int o = 0; o < 64; ++o) acc1[o] = -3.4e38f;
  } else {
#pragma unroll
    for (int o = 0; o < C; ++o) { acc1[o] = 0.f; acc2[o] = 0.f; }
  }

  for (int kk = 0; kk < 4; ++kk) {
    int nid = kb[kk];
    float4 R = xb[nid];
    float4 P = pb[nid];
    float x0[6] = {R.x - Q.x, R.y - Q.y, R.z - Q.z, P.x, P.y, P.z};
    float h[32];
#pragma unroll
    for (int o = 0; o < 32; ++o) {
      float a = w0[o * 6] * x0[0];
#pragma unroll
      for (int c = 1; c < 6; ++c) a = fmaf(w0[o * 6 + c], x0[c], a);
      h[o] = a;
    }
    if constexpr (STAGE == 0) {
#pragma unroll
      for (int o = 0; o < 32; ++o) { acc1[o] += h[o]; acc2[o] = fmaf(h[o], h[o], acc2[o]); }
    } else {
#pragma unroll
      for (int o = 0; o < 32; ++o) h[o] = fmaxf(fmaf(h[o], ab[o], ab[64 + o]), 0.f);
      float h1[32];
#pragma unroll
      for (int o = 0; o < 32; ++o) {
        float a = 0.f;
#pragma unroll
        for (int i = 0; i < 32; ++i) a = fmaf(w1[o * 32 + i], h[i], a);
        h1[o] = a;
      }
      if constexpr (STAGE == 1) {
#pragma unroll
        for (int o = 0; o < 32; ++o) { acc1[o] += h1[o]; acc2[o] = fmaf(h1[o], h1[o], acc2[o]); }
      } else {
#pragma unroll
        for (int o = 0; o < 32; ++o) h1[o] = fmaxf(fmaf(h1[o], ab[128 + o], ab[192 + o]), 0.f);
#pragma unroll
        for (int o = 0; o < 64; ++o) {
          float a = 0.f;
#pragma unroll
          for (int i = 0; i < 32; ++i) a = fmaf(w2[o * 32 + i], h1[i], a);
          if constexpr (STAGE == 2) {
            acc1[o] += a;
            acc2[o] = fmaf(a, a, acc2[o]);
          } else {
            acc1[o] = fmaxf(acc1[o], fmaxf(fmaf(a, ab[256 + o], ab[320 + o]), 0.f));
          }
        }
      }
    }
  }

  if constexpr (STAGE < 3) {
    // wave shuffle reduce -> per-wave slot -> per-block partial
#pragma unroll
    for (int o = 0; o < C; ++o) {
      float v1 = acc1[o], v2 = acc2[o];
#pragma unroll
      for (int d = 1; d < 64; d <<= 1) { v1 += __shfl_xor(v1, d); v2 += __shfl_xor(v2, d); }
      acc1[o] = v1; acc2[o] = v2;
    }
    if (lane == 0) {
#pragma unroll
      for (int o = 0; o < C; ++o) {
        smem[wid * 2 * C + o] = acc1[o];
        smem[wid * 2 * C + C + o] = acc2[o];
      }
    }
    __syncthreads();
    if (tid < 2 * C) {
      float v = smem[tid] + smem[2 * C + tid] + smem[4 * C + tid] + smem[6 * C + tid];
      partials[blk * 128 + tid] = v;
    }
  } else {
#pragma unroll
    for (int o = 0; o < 64; ++o) smem[ksec * 2048 + o * 32 + sl] = acc1[o];
    __syncthreads();
#pragma unroll
    for (int i = 0; i < 8; ++i) {
      int e = i * 256 + tid;
      int ch = e >> 5, ss = e & 31;
      float v = smem[ch * 32 + ss];
#pragma unroll
      for (int ks = 1; ks < 8; ++ks) v = fmaxf(v, smem[ks * 2048 + ch * 32 + ss]);
      out_np[b * 64 * NS + ch * NS + s0 + ss] = v;
    }
  }
}

__global__ __launch_bounds__(256) void finalize_kernel(const float* __restrict__ partials,
                                                       const float* __restrict__ g,
                                                       const float* __restrict__ bt,
                                                       float* __restrict__ ab, int C) {
  __shared__ float sm[256];
  int tid = threadIdx.x;
  int ch = tid & 127, half = tid >> 7;
  float acc = 0.f;
  if (ch < 2 * C) {
    const float* p = partials + half * 256 * 128 + ch;
    for (int i = 0; i < 256; ++i) acc += p[i * 128];
  }
  sm[half * 128 + ch] = acc;
  __syncthreads();
  if (tid < C) {
    float s1 = sm[tid] + sm[128 + tid];
    float s2 = sm[C + tid] + sm[128 + C + tid];
    const float ninv = 1.0f / 524288.0f;  // B*S*K
    float mean = s1 * ninv;
    float var = s2 * ninv - mean * mean;
    float inv = 1.0f / sqrtf(var + 1e-5f);
    float a = g[tid] * inv;
    ab[tid] = a;
    ab[64 + tid] = bt[tid] - mean * a;
  }
}

// ---------------------------------------------------------------------------
extern "C" void kernel_launch(void* const* d_in, const int* in_sizes, int n_in,
                              void* d_out, int out_size, void* d_ws, size_t ws_size,
                              hipStream_t stream) {
  const float* xyz = (const float*)d_in[0];
  const float* pts = (const float*)d_in[1];
  const float* w0 = (const float*)d_in[2];
  const float* g0 = (const float*)d_in[3];
  const float* b0 = (const float*)d_in[4];
  const float* w1 = (const float*)d_in[5];
  const float* g1 = (const float*)d_in[6];
  const float* b1 = (const float*)d_in[7];
  const float* w2 = (const float*)d_in[8];
  const float* g2 = (const float*)d_in[9];
  const float* b2 = (const float*)d_in[10];
  float* out = (float*)d_out;
  float* ws = (float*)d_ws;

  float4* xyz4 = (float4*)ws;                  // 262144 floats
  float4* pts4 = (float4*)(ws + 262144);       // 262144
  float4* nxyz4 = (float4*)(ws + 524288);      // 65536
  int* knn = (int*)(ws + 589824);              // 524288 ints
  float* partials = ws + 1114112;              // 3 * 65536
  float* ab = ws + 1310720;                    // 384
  float* out_np = out + 49152;                 // new_points [8,64,2048]
  float* out_fps = out + 1097728;              // fps_idx as float [8,2048]

  prep_kernel<<<256, 256, 0, stream>>>(xyz, pts, xyz4, pts4);
  fps_kernel<<<NB, 256, 0, stream>>>(xyz4, out, out_fps, nxyz4);
  knn_kernel<<<256, 256, 0, stream>>>(xyz4, nxyz4, knn);

  mlp_kernel<0><<<512, 256, 0, stream>>>(xyz4, pts4, nxyz4, knn, w0, w1, w2, ab, partials, nullptr);
  finalize_kernel<<<1, 256, 0, stream>>>(partials, g0, b0, ab, 32);
  mlp_kernel<1><<<512, 256, 0, stream>>>(xyz4, pts4, nxyz4, knn, w0, w1, w2, ab, partials + 65536, nullptr);
  finalize_kernel<<<1, 256, 0, stream>>>(partials + 65536, g1, b1, ab + 128, 32);
  mlp_kernel<2><<<512, 256, 0, stream>>>(xyz4, pts4, nxyz4, knn, w0, w1, w2, ab, partials + 131072, nullptr);
  finalize_kernel<<<1, 256, 0, stream>>>(partials + 131072, g2, b2, ab + 256, 64);
  mlp_kernel<3><<<512, 256, 0, stream>>>(xyz4, pts4, nxyz4, knn, w0, w1, w2, ab, nullptr, out_np);
}

// Round 4
// 2958.144 us; speedup vs baseline: 1.3000x; 1.3000x over previous
//
#include <hip/hip_runtime.h>
#include <hip/hip_bf16.h>
#include <math.h>

// ---------------------------------------------------------------------------
// PointNet++ Set Abstraction: FPS -> kNN -> grouped MLP(6->32->32->64) with
// BatchNorm(training stats) + ReLU -> max over K.
// B=8, N=8192, S=2048, K=32. All fp32.
//
// d_out layout (floats): new_xyz [8,3,2048] | new_points [8,64,2048] | fps_idx [8,2048]
// ---------------------------------------------------------------------------

#define NB 8
#define NN 8192
#define NS 2048
#define NK 32

// ---------------- prep: transpose to [B,N,4] with w = |p|^2 -----------------
__global__ __launch_bounds__(256) void prep_kernel(const float* __restrict__ xyz,
                                                   const float* __restrict__ pts,
                                                   float4* __restrict__ xyz4,
                                                   float4* __restrict__ pts4) {
  int g = blockIdx.x * 256 + threadIdx.x;      // 65536 = B*N
  int b = g >> 13, n = g & 8191;
  const float* xb = xyz + b * 3 * NN;
  float x = xb[n], y = xb[NN + n], z = xb[2 * NN + n];
  xyz4[g] = make_float4(x, y, z, fmaf(x, x, fmaf(y, y, z * z)));
  const float* pb = pts + b * 3 * NN;
  pts4[g] = make_float4(pb[n], pb[NN + n], pb[2 * NN + n], 0.f);
}

// ---------------- Hilbert-key counting sort (locality only; order is
// IRRELEVANT to correctness - FPS argmax is exact regardless of ordering) -----
__device__ __forceinline__ unsigned hkey(float x, float y, float z) {
  unsigned X[3];
  X[0] = (unsigned)min(15, max(0, (int)((x + 4.0f) * 2.0f)));
  X[1] = (unsigned)min(15, max(0, (int)((y + 4.0f) * 2.0f)));
  X[2] = (unsigned)min(15, max(0, (int)((z + 4.0f) * 2.0f)));
  // Skilling AXEStoTRANSPOSE (n=3, b=4)
  unsigned M = 8, P, Q, t;
  for (Q = M; Q > 1; Q >>= 1) {
    P = Q - 1;
#pragma unroll
    for (int i = 0; i < 3; ++i) {
      if (X[i] & Q) X[0] ^= P;
      else { t = (X[0] ^ X[i]) & P; X[0] ^= t; X[i] ^= t; }
    }
  }
#pragma unroll
  for (int i = 1; i < 3; ++i) X[i] ^= X[i - 1];
  t = 0;
  for (Q = M; Q > 1; Q >>= 1) if (X[2] & Q) t ^= Q - 1;
#pragma unroll
  for (int i = 0; i < 3; ++i) X[i] ^= t;
  unsigned key = 0;
#pragma unroll
  for (int bit = 3; bit >= 0; --bit)
#pragma unroll
    for (int i = 0; i < 3; ++i)
      key = (key << 1) | ((X[i] >> bit) & 1u);
  return key;  // 12 bits
}

__global__ __launch_bounds__(256) void sort_kernel(const float4* __restrict__ xyz4,
                                                   float4* __restrict__ sx) {
  __shared__ unsigned hist[4096];
  __shared__ unsigned wtot[4];
  int b = blockIdx.x, tid = threadIdx.x;
  int lane = tid & 63, wid = tid >> 6;
  const float4* xb = xyz4 + b * NN;
#pragma unroll
  for (int i = 0; i < 16; ++i) hist[i * 256 + tid] = 0;
  __syncthreads();
  for (int j = 0; j < 32; ++j) {
    float4 p = xb[j * 256 + tid];
    atomicAdd(&hist[hkey(p.x, p.y, p.z)], 1u);
  }
  __syncthreads();
  // block exclusive scan over 4096 buckets: 16 serial per thread + wave scan
  unsigned v[16], run = 0;
  int base = tid * 16;
#pragma unroll
  for (int i = 0; i < 16; ++i) { unsigned tt = hist[base + i]; v[i] = run; run += tt; }
  unsigned incl = run;
  for (int d = 1; d < 64; d <<= 1) { unsigned o = __shfl_up(incl, d); if (lane >= d) incl += o; }
  if (lane == 63) wtot[wid] = incl;
  __syncthreads();
  unsigned woff = 0;
  for (int w = 0; w < 4; ++w) woff += (w < wid) ? wtot[w] : 0;
  unsigned excl = incl - run + woff;
#pragma unroll
  for (int i = 0; i < 16; ++i) hist[base + i] = v[i] + excl;
  __syncthreads();
  for (int j = 0; j < 32; ++j) {
    int g = j * 256 + tid;
    float4 p = xb[g];
    unsigned slot = atomicAdd(&hist[hkey(p.x, p.y, p.z)], 1u);
    sx[b * NN + slot] = make_float4(p.x, p.y, p.z, __uint_as_float((unsigned)g));
  }
}

// ---------------- FPS v5: exact spatial pruning ------------------------------
// History: R1 (512thr, no pruning) 1785us; R2 (pk asm) 1957us REGRESS;
// R3 (256thr, 1 wave/SIMD) 2865us REGRESS - lost latency hiding; need >=2
// waves/SIMD. Fixed per-iter distance work (576cyc/CU) is the floor -> prune it:
//   * points Hilbert-sorted: thread's 16 points = compact blob; per-thread bbox.
//   * skip test: bound(centroid,bbox) >= cached per-thread max dist => that
//     thread's min-updates are provably identity. Wave skips distance+reduce
//     entirely iff ALL 64 lanes prunable (exec granularity); cached wave key
//     (wmax,min-gid) stays valid since dist unchanged.
//   * EXACTNESS: bound uses RN ops, same order as d; RN is monotone =>
//     bound <= true d for every point in bbox => skipped update is identity.
//     Winner's wave has bound=0 -> always updates. Selection = exact
//     lexicographic (max dist, min orig gid) at thread/wave/block level ==
//     reference first-occurrence argmax. absmax must stay exactly 2.976562.
//   * gid-aware reduce: DPP fmax for value + DPP umin for tie gid (no ballot;
//     lane order no longer == gid order after sort).
template <int CTRL>
__device__ __forceinline__ float dpp_max(float v) {
  int o = __builtin_amdgcn_update_dpp(__float_as_int(v), __float_as_int(v),
                                      CTRL, 0xf, 0xf, false);
  return fmaxf(v, __int_as_float(o));
}
template <int CTRL>
__device__ __forceinline__ unsigned dpp_umin(unsigned v) {
  unsigned o = (unsigned)__builtin_amdgcn_update_dpp((int)v, (int)v, CTRL, 0xf, 0xf, false);
  return v < o ? v : o;
}

__global__ __launch_bounds__(512, 1) void fps_kernel(const float4* __restrict__ xyz4,
                                                     const float4* __restrict__ sx,
                                                     float* __restrict__ out_nxyz,
                                                     float* __restrict__ out_fps,
                                                     float4* __restrict__ nxyz4) {
#pragma clang fp contract(off)
  int b = blockIdx.x, tid = threadIdx.x;
  int lane = tid & 63, wid = tid >> 6;           // 8 waves, 2 per SIMD
  __shared__ float4 tbl[NN];                     // coords by ORIGINAL gid
  __shared__ __align__(16) unsigned long long kslot[2][8];
  const float4* sb = sx + b * NN;

  float px[16], py[16], pz[16], dist[16];
  unsigned gid[16];
#pragma unroll
  for (int j = 0; j < 16; ++j) {
    float4 t = sb[(tid << 4) + j];
    px[j] = t.x; py[j] = t.y; pz[j] = t.z;
    gid[j] = __float_as_uint(t.w);
    dist[j] = 1e10f;
    tbl[gid[j]] = t;                             // scatter; .w unused
  }
  // per-thread bbox (one-time)
  float lox = px[0], loy = py[0], loz = pz[0];
  float hix = px[0], hiy = py[0], hiz = pz[0];
#pragma unroll
  for (int j = 1; j < 16; ++j) {
    lox = fminf(lox, px[j]); hix = fmaxf(hix, px[j]);
    loy = fminf(loy, py[j]); hiy = fmaxf(hiy, py[j]);
    loz = fminf(loz, pz[j]); hiz = fmaxf(hiz, pz[j]);
  }

  float4 c0 = xyz4[b * NN];                      // original index 0
  float cx = c0.x, cy = c0.y, cz = c0.z;
  float* onx = out_nxyz + b * 3 * NS;
  if (tid == 0) {
    nxyz4[b * NS] = c0;
    onx[0] = c0.x;
    onx[NS] = c0.y;
    onx[2 * NS] = c0.z;
    out_fps[b * NS] = 0.f;
  }

  float best = 1e10f;                 // cached per-thread max of dist
  unsigned long long wkey = 0;        // cached per-wave (wmax, min-gid) key

  for (int s = 1; s < NS; ++s) {
    // lower bound of centroid->point distance over this thread's bbox.
    // RN + same op order as d => monotone => bound <= d for all own points.
    float bx = fmaxf(fmaxf(lox - cx, cx - hix), 0.0f);
    float by = fmaxf(fmaxf(loy - cy, cy - hiy), 0.0f);
    float bz = fmaxf(fmaxf(loz - cz, cz - hiz), 0.0f);
    float bound = (bx * bx + by * by) + bz * bz;
    bool need = bound < best;         // else: all own updates provably identity
    if (__any(need)) {
      // exact (no-FMA, RN, left-to-right) distance + running min
#pragma unroll
      for (int j = 0; j < 16; ++j) {
        float dx = px[j] - cx;
        float dy = py[j] - cy;
        float dz = pz[j] - cz;
        float d = (dx * dx + dy * dy) + dz * dz;
        dist[j] = fminf(dist[j], d);
      }
      // thread max value: pairwise tree
      float t8[8];
#pragma unroll
      for (int j = 0; j < 8; ++j) t8[j] = fmaxf(dist[j], dist[j + 8]);
      float t4[4];
#pragma unroll
      for (int j = 0; j < 4; ++j) t4[j] = fmaxf(t8[j], t8[j + 4]);
      best = fmaxf(fmaxf(t4[0], t4[2]), fmaxf(t4[1], t4[3]));
      // wave max value via DPP, result in lane 63
      float mm = best;
      mm = dpp_max<0x111>(mm);
      mm = dpp_max<0x112>(mm);
      mm = dpp_max<0x114>(mm);
      mm = dpp_max<0x118>(mm);
      mm = dpp_max<0x142>(mm);
      mm = dpp_max<0x143>(mm);
      float wmax = __int_as_float(__builtin_amdgcn_readlane(__float_as_int(mm), 63));
      // thread min-gid among ties with best
      unsigned s8[8];
#pragma unroll
      for (int j = 0; j < 8; ++j) {
        unsigned a = (dist[j] == best) ? gid[j] : 0xFFFFFFFFu;
        unsigned c2 = (dist[j + 8] == best) ? gid[j + 8] : 0xFFFFFFFFu;
        s8[j] = a < c2 ? a : c2;
      }
      unsigned s4[4];
#pragma unroll
      for (int j = 0; j < 4; ++j) s4[j] = s8[j] < s8[j + 4] ? s8[j] : s8[j + 4];
      unsigned s2a = s4[0] < s4[2] ? s4[0] : s4[2];
      unsigned s2b = s4[1] < s4[3] ? s4[1] : s4[3];
      unsigned tg = s2a < s2b ? s2a : s2b;
      // wave min-gid among lanes attaining wmax
      unsigned cg = (best == wmax) ? tg : 0xFFFFFFFFu;
      cg = dpp_umin<0x111>(cg);
      cg = dpp_umin<0x112>(cg);
      cg = dpp_umin<0x114>(cg);
      cg = dpp_umin<0x118>(cg);
      cg = dpp_umin<0x142>(cg);
      cg = dpp_umin<0x143>(cg);
      unsigned gmin = (unsigned)__builtin_amdgcn_readlane((int)cg, 63);
      wkey = (((unsigned long long)__float_as_uint(wmax)) << 32) |
             (unsigned)(8191 - gmin);  // u64-max => max val, min gid
    }
    if (lane == 0) kslot[s & 1][wid] = wkey;
    __syncthreads();

    // block-wide reduce over 8 wave slots (broadcast b128 reads, u64 tree)
    const ulonglong2* kv = (const ulonglong2*)kslot[s & 1];
    ulonglong2 q0 = kv[0], q1 = kv[1], q2 = kv[2], q3 = kv[3];
    unsigned long long a0 = q0.x > q0.y ? q0.x : q0.y;
    unsigned long long a1 = q1.x > q1.y ? q1.x : q1.y;
    unsigned long long a2 = q2.x > q2.y ? q2.x : q2.y;
    unsigned long long a3 = q3.x > q3.y ? q3.x : q3.y;
    unsigned long long b0 = a0 > a1 ? a0 : a1;
    unsigned long long b1 = a2 > a3 ? a2 : a3;
    unsigned long long km = b0 > b1 ? b0 : b1;
    int g = 8191 - (int)((unsigned)(km & 0xFFFFFFFFull) & 0x1FFFu);
    g = __builtin_amdgcn_readfirstlane(g);       // uniform -> scalar path

    float4 c = tbl[g];                           // LDS broadcast read
    cx = c.x; cy = c.y; cz = c.z;
    if (tid == 0) {
      nxyz4[b * NS + s] = c;
      onx[s] = c.x;
      onx[NS + s] = c.y;
      onx[2 * NS + s] = c.z;
      out_fps[b * NS + s] = (float)g;
    }
    // single barrier/iter: parity slot kslot[s&1]; iter s+2's write can only
    // happen after barrier s+1, which requires all threads done reading iter s
  }
}

// ---------------- kNN: idx packed into low 13 mantissa bits -----------------
__device__ __forceinline__ void insert32(float (&a)[32], float f) {
  // sorted ascending; keep 32 smallest. new[i] = min(a[i], max(a[i-1], f))
#pragma unroll
  for (int i = 31; i >= 1; --i) a[i] = fminf(a[i], fmaxf(a[i - 1], f));
  a[0] = fminf(a[0], f);
}

__global__ __launch_bounds__(256) void knn_kernel(const float4* __restrict__ xyz4,
                                                  const float4* __restrict__ nxyz4,
                                                  int* __restrict__ knn) {
  __shared__ float lbuf[256][33];  // +1 pad: conflict-free
  int b = blockIdx.x >> 5, tile = blockIdx.x & 31;
  int tid = threadIdx.x;
  int q = tid & 63, chunk = tid >> 6;  // 64 queries x 4 ref-chunks
  float4 Q = nxyz4[b * NS + tile * 64 + q];
  float qq = Q.w;
  float mx = -2.f * Q.x, my = -2.f * Q.y, mz = -2.f * Q.z;
  float arr[32];
#pragma unroll
  for (int i = 0; i < 32; ++i) arr[i] = __uint_as_float(0x7f7fffffu);

  const float4* refs = xyz4 + b * NN + chunk * 2048;
  int rbase = chunk * 2048;
  for (int r = 0; r < 2048; ++r) {
    float4 R = refs[r];  // uniform per wave -> scalar load
    float d = fmaf(R.x, mx, fmaf(R.y, my, fmaf(R.z, mz, R.w + qq)));
    d = fmaxf(d, 0.f);
    float f = __uint_as_float((__float_as_uint(d) & 0xFFFFE000u) | (unsigned)(rbase + r));
    if (f < arr[31]) insert32(arr, f);
  }
#pragma unroll
  for (int i = 0; i < 32; ++i) lbuf[tid][i] = arr[i];
  __syncthreads();
  if (tid < 64) {  // merge 4 chunks for query tid
    for (int c = 1; c < 4; ++c)
      for (int i = 0; i < 32; ++i) {
        float f = lbuf[c * 64 + tid][i];
        if (f < arr[31]) insert32(arr, f);
      }
    int base = (b * NS + tile * 64 + tid) * NK;
#pragma unroll
    for (int i = 0; i < 32; ++i) knn[base + i] = (int)(__float_as_uint(arr[i]) & 0x1FFFu);
  }
}

// ---------------- MLP passes (recompute; BN needs global stats) -------------
// STAGE 0: y0 stats | 1: ->y1 stats | 2: ->y2 stats | 3: full + maxK + out
template <int STAGE>
__global__ __launch_bounds__(256) void mlp_kernel(
    const float4* __restrict__ xyz4, const float4* __restrict__ pts4,
    const float4* __restrict__ nxyz4, const int* __restrict__ knn,
    const float* __restrict__ w0, const float* __restrict__ w1,
    const float* __restrict__ w2, const float* __restrict__ ab,
    float* __restrict__ partials, float* __restrict__ out_np) {
  constexpr int C = (STAGE == 2) ? 64 : 32;              // stats channels
  constexpr int SM = (STAGE == 3) ? 8 * 64 * 32 : 512;   // floats
  __shared__ float smem[SM];
  int blk = blockIdx.x;
  int b = blk >> 6, s0 = (blk & 63) * 32;
  int tid = threadIdx.x, sl = tid & 31, ksec = tid >> 5;
  int lane = tid & 63, wid = tid >> 6;
  int s = s0 + sl;
  float4 Q = nxyz4[b * NS + s];
  const float4* xb = xyz4 + b * NN;
  const float4* pb = pts4 + b * NN;
  const int* kb = knn + (b * NS + s) * NK + ksec * 4;

  float acc1[(STAGE == 3) ? 64 : C];
  float acc2[(STAGE == 3) ? 1 : C];
  if constexpr (STAGE == 3) {
#pragma unroll
    for (int o = 0; o < 64; ++o) acc1[o] = -3.4e38f;
  } else {
#pragma unroll
    for (int o = 0; o < C; ++o) { acc1[o] = 0.f; acc2[o] = 0.f; }
  }

  for (int kk = 0; kk < 4; ++kk) {
    int nid = kb[kk];
    float4 R = xb[nid];
    float4 P = pb[nid];
    float x0[6] = {R.x - Q.x, R.y - Q.y, R.z - Q.z, P.x, P.y, P.z};
    float h[32];
#pragma unroll
    for (int o = 0; o < 32; ++o) {
      float a = w0[o * 6] * x0[0];
#pragma unroll
      for (int c = 1; c < 6; ++c) a = fmaf(w0[o * 6 + c], x0[c], a);
      h[o] = a;
    }
    if constexpr (STAGE == 0) {
#pragma unroll
      for (int o = 0; o < 32; ++o) { acc1[o] += h[o]; acc2[o] = fmaf(h[o], h[o], acc2[o]); }
    } else {
#pragma unroll
      for (int o = 0; o < 32; ++o) h[o] = fmaxf(fmaf(h[o], ab[o], ab[64 + o]), 0.f);
      float h1[32];
#pragma unroll
      for (int o = 0; o < 32; ++o) {
        float a = 0.f;
#pragma unroll
        for (int i = 0; i < 32; ++i) a = fmaf(w1[o * 32 + i], h[i], a);
        h1[o] = a;
      }
      if constexpr (STAGE == 1) {
#pragma unroll
        for (int o = 0; o < 32; ++o) { acc1[o] += h1[o]; acc2[o] = fmaf(h1[o], h1[o], acc2[o]); }
      } else {
#pragma unroll
        for (int o = 0; o < 32; ++o) h1[o] = fmaxf(fmaf(h1[o], ab[128 + o], ab[192 + o]), 0.f);
#pragma unroll
        for (int o = 0; o < 64; ++o) {
          float a = 0.f;
#pragma unroll
          for (int i = 0; i < 32; ++i) a = fmaf(w2[o * 32 + i], h1[i], a);
          if constexpr (STAGE == 2) {
            acc1[o] += a;
            acc2[o] = fmaf(a, a, acc2[o]);
          } else {
            acc1[o] = fmaxf(acc1[o], fmaxf(fmaf(a, ab[256 + o], ab[320 + o]), 0.f));
          }
        }
      }
    }
  }

  if constexpr (STAGE < 3) {
    // wave shuffle reduce -> per-wave slot -> per-block partial
#pragma unroll
    for (int o = 0; o < C; ++o) {
      float v1 = acc1[o], v2 = acc2[o];
#pragma unroll
      for (int d = 1; d < 64; d <<= 1) { v1 += __shfl_xor(v1, d); v2 += __shfl_xor(v2, d); }
      acc1[o] = v1; acc2[o] = v2;
    }
    if (lane == 0) {
#pragma unroll
      for (int o = 0; o < C; ++o) {
        smem[wid * 2 * C + o] = acc1[o];
        smem[wid * 2 * C + C + o] = acc2[o];
      }
    }
    __syncthreads();
    if (tid < 2 * C) {
      float v = smem[tid] + smem[2 * C + tid] + smem[4 * C + tid] + smem[6 * C + tid];
      partials[blk * 128 + tid] = v;
    }
  } else {
#pragma unroll
    for (int o = 0; o < 64; ++o) smem[ksec * 2048 + o * 32 + sl] = acc1[o];
    __syncthreads();
#pragma unroll
    for (int i = 0; i < 8; ++i) {
      int e = i * 256 + tid;
      int ch = e >> 5, ss = e & 31;
      float v = smem[ch * 32 + ss];
#pragma unroll
      for (int ks = 1; ks < 8; ++ks) v = fmaxf(v, smem[ks * 2048 + ch * 32 + ss]);
      out_np[b * 64 * NS + ch * NS + s0 + ss] = v;
    }
  }
}

__global__ __launch_bounds__(256) void finalize_kernel(const float* __restrict__ partials,
                                                       const float* __restrict__ g,
                                                       const float* __restrict__ bt,
                                                       float* __restrict__ ab, int C) {
  __shared__ float sm[256];
  int tid = threadIdx.x;
  int ch = tid & 127, half = tid >> 7;
  float acc = 0.f;
  if (ch < 2 * C) {
    const float* p = partials + half * 256 * 128 + ch;
    for (int i = 0; i < 256; ++i) acc += p[i * 128];
  }
  sm[half * 128 + ch] = acc;
  __syncthreads();
  if (tid < C) {
    float s1 = sm[tid] + sm[128 + tid];
    float s2 = sm[C + tid] + sm[128 + C + tid];
    const float ninv = 1.0f / 524288.0f;  // B*S*K
    float mean = s1 * ninv;
    float var = s2 * ninv - mean * mean;
    float inv = 1.0f / sqrtf(var + 1e-5f);
    float a = g[tid] * inv;
    ab[tid] = a;
    ab[64 + tid] = bt[tid] - mean * a;
  }
}

// ---------------------------------------------------------------------------
extern "C" void kernel_launch(void* const* d_in, const int* in_sizes, int n_in,
                              void* d_out, int out_size, void* d_ws, size_t ws_size,
                              hipStream_t stream) {
  const float* xyz = (const float*)d_in[0];
  const float* pts = (const float*)d_in[1];
  const float* w0 = (const float*)d_in[2];
  const float* g0 = (const float*)d_in[3];
  const float* b0 = (const float*)d_in[4];
  const float* w1 = (const float*)d_in[5];
  const float* g1 = (const float*)d_in[6];
  const float* b1 = (const float*)d_in[7];
  const float* w2 = (const float*)d_in[8];
  const float* g2 = (const float*)d_in[9];
  const float* b2 = (const float*)d_in[10];
  float* out = (float*)d_out;
  float* ws = (float*)d_ws;

  float4* xyz4 = (float4*)ws;                  // 262144 floats
  float4* pts4 = (float4*)(ws + 262144);       // 262144
  float4* nxyz4 = (float4*)(ws + 524288);      // 65536
  int* knn = (int*)(ws + 589824);              // 524288 ints
  float* partials = ws + 1114112;              // 3 * 65536
  float* ab = ws + 1310720;                    // 384
  float* out_np = out + 49152;                 // new_points [8,64,2048]
  float* out_fps = out + 1097728;              // fps_idx as float [8,2048]

  // sorted points live in the knn region (1MB < 2MB): fps reads them BEFORE
  // knn_kernel writes indices there. Same stream => ordered.
  float4* sx = (float4*)knn;

  prep_kernel<<<256, 256, 0, stream>>>(xyz, pts, xyz4, pts4);
  sort_kernel<<<NB, 256, 0, stream>>>(xyz4, sx);
  fps_kernel<<<NB, 512, 0, stream>>>(xyz4, sx, out, out_fps, nxyz4);
  knn_kernel<<<256, 256, 0, stream>>>(xyz4, nxyz4, knn);

  mlp_kernel<0><<<512, 256, 0, stream>>>(xyz4, pts4, nxyz4, knn, w0, w1, w2, ab, partials, nullptr);
  finalize_kernel<<<1, 256, 0, stream>>>(partials, g0, b0, ab, 32);
  mlp_kernel<1><<<512, 256, 0, stream>>>(xyz4, pts4, nxyz4, knn, w0, w1, w2, ab, partials + 65536, nullptr);
  finalize_kernel<<<1, 256, 0, stream>>>(partials + 65536, g1, b1, ab + 128, 32);
  mlp_kernel<2><<<512, 256, 0, stream>>>(xyz4, pts4, nxyz4, knn, w0, w1, w2, ab, partials + 131072, nullptr);
  finalize_kernel<<<1, 256, 0, stream>>>(partials + 131072, g2, b2, ab + 256, 64);
  mlp_kernel<3><<<512, 256, 0, stream>>>(xyz4, pts4, nxyz4, knn, w0, w1, w2, ab, nullptr, out_np);
}